// Round 13
// baseline (335.576 us; speedup 1.0000x reference)
//
#include <hip/hip_runtime.h>
#include <cmath>

#define D_MODEL 768
#define SEQ 2048
#define BATCH 8
#define FC_PAD 96
#define FC_PAD2 128
#define KCOMB (7 * D_MODEL)   // 5376
#define KCHUNK 1344           // KCOMB/4

typedef unsigned short ushort_t;
typedef _Float16 half_t;
typedef __attribute__((ext_vector_type(8))) _Float16 f16x8;
typedef __attribute__((ext_vector_type(8))) unsigned short u16x8;
typedef __attribute__((ext_vector_type(4))) unsigned short u16x4;
typedef __attribute__((ext_vector_type(4))) float f32x4;

struct Ptr8 { const ushort_t* p[8]; };

__device__ __forceinline__ ushort_t f2h(float x) {
    half_t h = (half_t)x;
    return __builtin_bit_cast(ushort_t, h);
}
__device__ __forceinline__ float h2f(ushort_t u) {
    return (float)__builtin_bit_cast(half_t, u);
}
__device__ __forceinline__ float fast_tanh(float x) {
    float a = fabsf(x);
    float t = __expf(-2.f * a);
    float r = (1.f - t) / (1.f + t);
    return copysignf(r, x);
}
__device__ __forceinline__ void gload16(const ushort_t* g, ushort_t* lbase) {
    __builtin_amdgcn_global_load_lds((const __attribute__((address_space(1))) void*)g,
                                     (__attribute__((address_space(3))) void*)lbase,
                                     16, 0, 0);
}

// ---------------- prep kernels ----------------
__global__ void convert_f16_kernel(const float* __restrict__ src, ushort_t* __restrict__ dst, size_t n4) {
    size_t i = (size_t)blockIdx.x * 256 + threadIdx.x;
    if (i >= n4) return;
    f32x4 x = *(const f32x4*)(src + i * 4);
    u16x4 h;
    #pragma unroll
    for (int j = 0; j < 4; ++j) h[j] = f2h(x[j]);
    *(u16x4*)(dst + i * 4) = h;
}

// x2 fp32 -> x2_h [8][2048][768] fp16 AND x2t [8][768][2048] fp16, one pass
__global__ void convert_x2_kernel(const float* __restrict__ in,
                                  ushort_t* __restrict__ x2h, ushort_t* __restrict__ x2t) {
    __shared__ ushort_t tile[32][33];
    int b = blockIdx.z;
    int s0 = blockIdx.x * 32, d0 = blockIdx.y * 32;
    int tx = threadIdx.x & 31, ty = threadIdx.x >> 5;   // 32 x 8
    const float* inb = in + (size_t)b * SEQ * D_MODEL;
    ushort_t* hb = x2h + (size_t)b * SEQ * D_MODEL;
    ushort_t* tb = x2t + (size_t)b * D_MODEL * SEQ;
    #pragma unroll
    for (int i = 0; i < 4; ++i) {
        int s = s0 + ty + i * 8;
        ushort_t h = f2h(inb[(size_t)s * D_MODEL + d0 + tx]);
        hb[(size_t)s * D_MODEL + d0 + tx] = h;
        tile[ty + i * 8][tx] = h;
    }
    __syncthreads();
    #pragma unroll
    for (int i = 0; i < 4; ++i)
        tb[(size_t)(d0 + ty + i * 8) * SEQ + s0 + tx] = tile[tx][ty + i * 8];
}

// all weight prep in one dispatch: Wcomb fp16 [128][5376] (rows 90..127 zero),
// fc_wt [768][128] zero-padded, fcx_wt [768][1536], Ut [n][k]=U[k][n], bcat[128]
#define R0 (FC_PAD2 * KCOMB)                 // 688128
#define R1 (D_MODEL * FC_PAD2)               // 98304
#define R2 (D_MODEL * 2 * D_MODEL)           // 1179648
#define R3 (D_MODEL * D_MODEL)               // 589824
__global__ void prep_weights_kernel(const float* __restrict__ w7, const float* __restrict__ b7,
                                    const float* __restrict__ w5, const float* __restrict__ b5,
                                    const float* __restrict__ w3, const float* __restrict__ b3,
                                    const float* __restrict__ fc_w, const float* __restrict__ fcx_w,
                                    const float* __restrict__ U,
                                    ushort_t* __restrict__ Wt, ushort_t* __restrict__ fc_wt,
                                    ushort_t* __restrict__ fcx_wt, ushort_t* __restrict__ Ut,
                                    float* __restrict__ bcat) {
    int idx = blockIdx.x * 256 + threadIdx.x;
    if (idx < R0) {
        int o = idx / KCOMB, k = idx - o * KCOMB;
        int t = k / D_MODEL, d = k - t * D_MODEL;
        float v = 0.f;
        if (o < 40) {
            v = w7[(size_t)o * (D_MODEL * 7) + d * 7 + t];
        } else if (o < 70) {
            int t5 = t - 1;
            if (t5 >= 0 && t5 < 5) v = w5[(size_t)(o - 40) * (D_MODEL * 5) + d * 5 + t5];
        } else if (o < 90) {
            int t3 = t - 2;
            if (t3 >= 0 && t3 < 3) v = w3[(size_t)(o - 70) * (D_MODEL * 3) + d * 3 + t3];
        }
        Wt[idx] = f2h(v);
        return;
    }
    idx -= R0;
    if (idx < R1) {
        int o = idx / FC_PAD2, j = idx - o * FC_PAD2;
        fc_wt[idx] = (j < 90) ? f2h(fc_w[o * 90 + j]) : 0;
        return;
    }
    idx -= R1;
    if (idx < R2) {
        fcx_wt[idx] = f2h(fcx_w[idx]);
        return;
    }
    idx -= R2;
    if (idx < R3) {
        int n = idx / D_MODEL, k = idx - n * D_MODEL;
        Ut[idx] = f2h(U[(size_t)k * D_MODEL + n]);
        return;
    }
    idx -= R3;
    if (idx < FC_PAD2) {
        float bv = 0.f;
        if (idx < 40) bv = b7[idx];
        else if (idx < 70) bv = b5[idx - 40];
        else if (idx < 90) bv = b3[idx - 70];
        bcat[idx] = bv;
    }
}

// ---------------- fp16 MFMA GEMM, BK=64, 128B LDS rows + XOR slot swizzle ----------------
// C[M,N] = epilogue( A' @ B'^T ); A' [M][K] fp16, B' [N][K] fp16 (N-major).
// 4 waves (2x2), wave tile 64x64. LDS rows: 64 elems (8 x 16B slots),
// slot ^= (row&7) folded into the GLOBAL source address (rule #21).
// AMODE: 0 plain, 1 im2col(x2_h, VGPR-staged), 2 concat(A|A2, stride 768),
//        3 conv-partials fuse: A'=relu(P0+P1+P2+P3+bcat) fp16, cols>=96 zero
//          (A = convp as float*, A2 = bcat as float*, lda = FC_PAD)
// KSPLIT: blockIdx.z = K-chunk; APTR: A base = ap.p[z]
// MAP: 0 3D grid; 1 lin->{z=lin%ZM, bx=t%GX, by=t/GX}; 2 lin->{xcd A-slice, by fast};
//      3 lin->{z=lin%ZM, by=t%GY, bx=t/GY}  (by fastest: A-panel L2-hot)
// SMEPI: tile-softmax epilogue — P'=exp(S-m_tile128) fp16 -> ap.p[z]; stats -> smw/slw.
// ASCALE: PV mode — prologue builds fp16 alpha[16][128] from stats; A-frags scaled.
template<int TM, int TN, int AMODE, int ACT, int HASBIAS, int HASADD,
         int OUTMODE, int KSPLIT, int APTR, int MAP, int ZM, int GX, int GY,
         int SMEPI, int ASCALE>
__global__ __launch_bounds__(256, 4)
void mfma_gemm(const ushort_t* __restrict__ A, const ushort_t* __restrict__ A2,
               const ushort_t* __restrict__ B, const float* __restrict__ bias,
               const ushort_t* __restrict__ addsrc,
               float* __restrict__ Cf, ushort_t* __restrict__ Ch,
               Ptr8 ap, float* __restrict__ smw, float* __restrict__ slw,
               int M, int N, int K, int lda, int ldb, int ldc,
               size_t sA, size_t sB, size_t sBias, size_t sC) {
    constexpr int WM = TM / 2, WN = TN / 2, FM = WM / 16, FN = WN / 16;
    __shared__ __align__(16) ushort_t As_[TM * 64];
    __shared__ __align__(16) ushort_t Bs_[TN * 64];
    __shared__ float pmS[SMEPI ? 4 : 1][SMEPI ? 64 : 1];
    __shared__ float msS[SMEPI ? 128 : 1];
    __shared__ float plS[SMEPI ? 4 : 1][SMEPI ? 64 : 1];
    __shared__ ushort_t alS[ASCALE ? 16 : 1][ASCALE ? 128 : 1];   // fp16 alpha

    int bx, by, z;
    if (MAP == 1) {
        int lin = blockIdx.x;
        z = lin % ZM;
        int t = lin / ZM;
        bx = t % GX;
        by = t / GX;
    } else if (MAP == 2) {
        int lin = blockIdx.x;
        int xcd = lin & 7;
        int t = lin >> 3;
        by = t % GY;
        bx = xcd * (GX / 8) + t / GY;
        z = 0;
    } else if (MAP == 3) {
        int lin = blockIdx.x;
        z = lin % ZM;
        int t = lin / ZM;
        by = t % GY;
        bx = t / GY;
    } else {
        bx = blockIdx.x; by = blockIdx.y; z = blockIdx.z;
    }

    const int kb = KSPLIT ? z * K : 0;
    const ushort_t* Ab = APTR ? ap.p[z] : (A + (KSPLIT ? 0 : (size_t)z * sA));
    const ushort_t* Bb = B + (KSPLIT ? 0 : (size_t)z * sB);
    if (HASBIAS) bias += (size_t)z * sBias;
    if (HASADD) addsrc += (size_t)z * sC;
    if (OUTMODE == 0) Cf += (size_t)z * sC;
    else if (!SMEPI) Ch += (size_t)z * sC;

    const int m0 = bx * TM;
    const int n0 = by * TN;
    const int tid = threadIdx.x;
    const int lane = tid & 63;
    const int wave = tid >> 6;
    const int wm = (wave >> 1) * WM, wn = (wave & 1) * WN;
    const int r16 = lane & 15, kq = lane >> 4;
    const int srow = tid >> 3;          // 0..31
    const int slot = tid & 7;           // 16B slot (LDS-linear)

    // ---- ASCALE prologue: fp16 alpha[tile16][row] from stats ----
    if (ASCALE) {
        if (tid < 128) {
            int row = tid;
            int gm = m0 + row;
            float mt[16], al[16];
            float mg = -3.0e38f;
            #pragma unroll
            for (int t = 0; t < 16; ++t) {
                mt[t] = smw[((size_t)z * 16 + t) * SEQ + gm];
                mg = fmaxf(mg, mt[t]);
            }
            float lg = 0.f;
            #pragma unroll
            for (int t = 0; t < 16; ++t) {
                float e = __expf(mt[t] - mg);
                lg += slw[((size_t)z * 16 + t) * SEQ + gm] * e;
                al[t] = e;
            }
            float inv = 1.f / lg;
            #pragma unroll
            for (int t = 0; t < 16; ++t) alS[t][row] = f2h(al[t] * inv);
        }
        __syncthreads();
    }

    f32x4 acc[FM][FN];
    #pragma unroll
    for (int i = 0; i < FM; ++i)
        #pragma unroll
        for (int j = 0; j < FN; ++j) acc[i][j] = (f32x4){0.f, 0.f, 0.f, 0.f};

    const u16x8 zv = {0, 0, 0, 0, 0, 0, 0, 0};

    for (int k0 = 0; k0 < K; k0 += 64) {
        // ---- stage A ----
        #pragma unroll
        for (int i = 0; i < TM / 32; ++i) {
            int row = i * 32 + srow;
            int gm = m0 + row;
            int xs = slot ^ (row & 7);
            if (AMODE == 1) {
                int gkk = kb + k0 + xs * 8;
                int t = gkk / D_MODEL, d = gkk - t * D_MODEL;
                int s = (gm & (SEQ - 1)) + t - 3;
                int bb = gm >> 11;
                u16x8 v = (s >= 0 && s < SEQ) ? *(const u16x8*)(Ab + ((size_t)(bb * SEQ + s)) * lda + d) : zv;
                *(u16x8*)&As_[(size_t)row * 64 + slot * 8] = v;
            } else if (AMODE == 3) {
                // A' = relu(sum of 4 conv partials + bcat) fp16, cols >= 96 zero
                int gk = k0 + xs * 8;       // multiple of 8; 96 % 8 == 0 -> no straddle
                u16x8 v = zv;
                if (gk < FC_PAD) {
                    const float* P = (const float*)Ab;
                    const float* bc = (const float*)A2;
                    const size_t st = (size_t)BATCH * SEQ * FC_PAD;
                    size_t base = (size_t)gm * FC_PAD + gk;
                    #pragma unroll
                    for (int h = 0; h < 2; ++h) {
                        f32x4 s0 = *(const f32x4*)(P + base + h * 4);
                        f32x4 s1 = *(const f32x4*)(P + st + base + h * 4);
                        f32x4 s2 = *(const f32x4*)(P + 2 * st + base + h * 4);
                        f32x4 s3 = *(const f32x4*)(P + 3 * st + base + h * 4);
                        f32x4 bcv = *(const f32x4*)(bc + gk + h * 4);
                        #pragma unroll
                        for (int j = 0; j < 4; ++j)
                            v[h * 4 + j] = f2h(fmaxf(s0[j] + s1[j] + s2[j] + s3[j] + bcv[j], 0.f));
                    }
                }
                *(u16x8*)&As_[(size_t)row * 64 + slot * 8] = v;
            } else {
                const ushort_t* src;
                if (AMODE == 2) {
                    int gk = k0 + xs * 8;
                    src = (gk < D_MODEL) ? Ab + (size_t)gm * D_MODEL + gk
                                         : A2 + (size_t)gm * D_MODEL + (gk - D_MODEL);
                } else {
                    int gk = kb + k0 + xs * 8;
                    src = Ab + (size_t)gm * lda + gk;
                }
                gload16(src, &As_[(size_t)(i * 32 + wave * 8) * 64]);
            }
        }
        // ---- stage B ----
        #pragma unroll
        for (int i = 0; i < TN / 32; ++i) {
            int row = i * 32 + srow;
            int gn = n0 + row;
            int xs = slot ^ (row & 7);
            int gk = kb + k0 + xs * 8;
            gload16(Bb + (size_t)gn * ldb + gk, &Bs_[(size_t)(i * 32 + wave * 8) * 64]);
        }
        __syncthreads();

        f16x8 ah[FM][2], bh[FN][2];
        #pragma unroll
        for (int mi = 0; mi < FM; ++mi) {
            int row = wm + mi * 16 + r16;
            #pragma unroll
            for (int kk = 0; kk < 2; ++kk)
                ah[mi][kk] = *(const f16x8*)&As_[(size_t)row * 64 + (((kk * 4 + kq) ^ (row & 7)) * 8)];
        }
        if (ASCALE) {
            const int kt = k0 >> 7;   // 128-col stats tile
            #pragma unroll
            for (int mi = 0; mi < FM; ++mi) {
                half_t s = __builtin_bit_cast(half_t, alS[kt][wm + mi * 16 + r16]);
                ah[mi][0] = ah[mi][0] * s;
                ah[mi][1] = ah[mi][1] * s;
            }
        }
        #pragma unroll
        for (int ni = 0; ni < FN; ++ni) {
            int row = wn + ni * 16 + r16;
            #pragma unroll
            for (int kk = 0; kk < 2; ++kk)
                bh[ni][kk] = *(const f16x8*)&Bs_[(size_t)row * 64 + (((kk * 4 + kq) ^ (row & 7)) * 8)];
        }
        #pragma unroll
        for (int kk = 0; kk < 2; ++kk)
            #pragma unroll
            for (int mi = 0; mi < FM; ++mi)
                #pragma unroll
                for (int ni = 0; ni < FN; ++ni)
                    acc[mi][ni] = __builtin_amdgcn_mfma_f32_16x16x32_f16(ah[mi][kk], bh[ni][kk], acc[mi][ni], 0, 0, 0);
        __syncthreads();
    }

    if (SMEPI) {
        // ---- tile-softmax epilogue (TM=TN=128, full tiles) ----
        float pmax[FM][4];
        #pragma unroll
        for (int mi = 0; mi < FM; ++mi)
            #pragma unroll
            for (int r = 0; r < 4; ++r) {
                float mx = -3.0e38f;
                #pragma unroll
                for (int ni = 0; ni < FN; ++ni) {
                    float v = acc[mi][ni][r];
                    if (HASBIAS) { v += bias[n0 + wn + ni * 16 + r16]; acc[mi][ni][r] = v; }
                    mx = fmaxf(mx, v);
                }
                mx = fmaxf(mx, __shfl_xor(mx, 1));
                mx = fmaxf(mx, __shfl_xor(mx, 2));
                mx = fmaxf(mx, __shfl_xor(mx, 4));
                mx = fmaxf(mx, __shfl_xor(mx, 8));
                pmax[mi][r] = mx;
            }
        if (r16 == 0) {
            #pragma unroll
            for (int mi = 0; mi < FM; ++mi)
                #pragma unroll
                for (int r = 0; r < 4; ++r)
                    pmS[wave][mi * 16 + kq * 4 + r] = pmax[mi][r];
        }
        __syncthreads();
        if (tid < 128) {                      // combine wn-halves
            int rl = tid & 63, grp = tid >> 6;
            msS[grp * 64 + rl] = fmaxf(pmS[grp * 2][rl], pmS[grp * 2 + 1][rl]);
        }
        __syncthreads();
        #pragma unroll
        for (int mi = 0; mi < FM; ++mi)
            #pragma unroll
            for (int r = 0; r < 4; ++r) {
                float mrow = msS[wm + mi * 16 + kq * 4 + r];
                float s = 0.f;
                #pragma unroll
                for (int ni = 0; ni < FN; ++ni) {
                    float e = __expf(acc[mi][ni][r] - mrow);
                    acc[mi][ni][r] = e;
                    s += e;
                }
                s += __shfl_xor(s, 1);
                s += __shfl_xor(s, 2);
                s += __shfl_xor(s, 4);
                s += __shfl_xor(s, 8);
                pmax[mi][r] = s;
            }
        if (r16 == 0) {
            #pragma unroll
            for (int mi = 0; mi < FM; ++mi)
                #pragma unroll
                for (int r = 0; r < 4; ++r)
                    plS[wave][mi * 16 + kq * 4 + r] = pmax[mi][r];
        }
        __syncthreads();
        if (tid < 128) {                      // write stats
            int rl = tid & 63, grp = tid >> 6;
            int row = grp * 64 + rl;
            float l2 = plS[grp * 2][rl] + plS[grp * 2 + 1][rl];
            size_t si = ((size_t)z * 16 + by) * SEQ + (m0 + row);
            smw[si] = msS[row];
            slw[si] = l2;
        }
        ushort_t* Co = (ushort_t*)ap.p[z];
        #pragma unroll
        for (int mi = 0; mi < FM; ++mi)
            #pragma unroll
            for (int ni = 0; ni < FN; ++ni)
                #pragma unroll
                for (int r = 0; r < 4; ++r) {
                    int gm = m0 + wm + mi * 16 + kq * 4 + r;
                    int gn = n0 + wn + ni * 16 + r16;
                    Co[(size_t)gm * SEQ + gn] = f2h(acc[mi][ni][r]);
                }
        return;
    }

    // ---- standard epilogue ----
    #pragma unroll
    for (int mi = 0; mi < FM; ++mi)
        #pragma unroll
        for (int ni = 0; ni < FN; ++ni)
            #pragma unroll
            for (int r = 0; r < 4; ++r) {
                int gm = m0 + wm + mi * 16 + kq * 4 + r;
                int gn = n0 + wn + ni * 16 + r16;
                if (gn >= N) continue;
                float v = acc[mi][ni][r];
                if (HASBIAS) v += bias[gn];
                if (ACT == 1) v = fmaxf(v, 0.f);
                else if (ACT == 2) v = fast_tanh(v);
                if (HASADD) v += h2f(addsrc[(size_t)gm * ldc + gn]);
                size_t idx = (size_t)gm * ldc + gn;
                if (OUTMODE == 0) Cf[idx] = v;
                else Ch[idx] = f2h(v);
            }
}

extern "C" void kernel_launch(void* const* d_in, const int* in_sizes, int n_in,
                              void* d_out, int out_size, void* d_ws, size_t ws_size,
                              hipStream_t stream) {
    const float* x1     = (const float*)d_in[0];
    const float* x2     = (const float*)d_in[1];
    const float* w7     = (const float*)d_in[2];
    const float* b7     = (const float*)d_in[3];
    const float* w5     = (const float*)d_in[4];
    const float* b5     = (const float*)d_in[5];
    const float* w3     = (const float*)d_in[6];
    const float* b3     = (const float*)d_in[7];
    const float* U      = (const float*)d_in[8];
    const float* bias_v = (const float*)d_in[9];
    const float* fc_w   = (const float*)d_in[10];
    const float* fc_b   = (const float*)d_in[11];
    const float* fcx_w  = (const float*)d_in[12];
    const float* fcx_b  = (const float*)d_in[13];
    float* out = (float*)d_out;

    const size_t MT = (size_t)BATCH * SEQ;      // 16384
    const size_t NE = MT * D_MODEL;             // 12.58M
    const size_t NEb = (size_t)SEQ * D_MODEL;   // per-batch elems
    const size_t SEGSZ = (size_t)SEQ * SEQ;     // P' batch elems (8.39MB fp16)

    char* p = (char*)d_ws;
    auto alloc = [&](size_t bytes) -> char* {
        char* r = p;
        p += (bytes + 255) & ~(size_t)255;
        return r;
    };
    ushort_t* x1_h   = (ushort_t*)alloc(NE * 2);
    ushort_t* x2_h   = (ushort_t*)alloc(NE * 2);
    ushort_t* x2t    = (ushort_t*)alloc(NE * 2);
    ushort_t* y1     = (ushort_t*)alloc(NE * 2);
    ushort_t* xcnn   = (ushort_t*)alloc(NE * 2);
    float*    convp  = (float*)   alloc(MT * FC_PAD * 4 * 4); // 4 fp32 partials; then 3 P' segs
    ushort_t* Wt     = (ushort_t*)alloc((size_t)FC_PAD2 * KCOMB * 2);
    ushort_t* fc_wt  = (ushort_t*)alloc((size_t)D_MODEL * FC_PAD2 * 2);
    ushort_t* fcx_wt = (ushort_t*)alloc((size_t)D_MODEL * 2 * D_MODEL * 2);
    ushort_t* Ut     = (ushort_t*)alloc((size_t)D_MODEL * D_MODEL * 2);
    float*    bcat   = (float*)alloc(FC_PAD2 * 4);
    float*    smS    = (float*)alloc((size_t)BATCH * 16 * SEQ * 4);  // tile row-max
    float*    slS    = (float*)alloc((size_t)BATCH * 16 * SEQ * 4);  // tile row-sum

    // P' segments (8 x 8.39MB): 3 in convp (dead after fc consumes partials), 5 in d_out
    ushort_t* dob = (ushort_t*)d_out;
    Ptr8 ap;
    ap.p[0] = (ushort_t*)convp;
    ap.p[1] = (ushort_t*)convp + SEGSZ;
    ap.p[2] = (ushort_t*)convp + 2 * SEGSZ;
    ap.p[3] = dob;
    ap.p[4] = dob + SEGSZ;
    ap.p[5] = dob + 2 * SEGSZ;
    ap.p[6] = dob + 3 * SEGSZ;
    ap.p[7] = dob + 4 * SEGSZ;
    Ptr8 apz = {};

    const int T = 256;
    auto blk = [](size_t n) { return dim3((unsigned)((n + 255) / 256)); };

    // ---- prep (3 dispatches) ----
    prep_weights_kernel<<<blk((size_t)R0 + R1 + R2 + R3 + FC_PAD2), T, 0, stream>>>(
        w7, b7, w5, b5, w3, b3, fc_w, fcx_w, U, Wt, fc_wt, fcx_wt, Ut, bcat);
    convert_f16_kernel<<<blk(NE / 4), T, 0, stream>>>(x1, x1_h, NE / 4);
    convert_x2_kernel<<<dim3(SEQ / 32, D_MODEL / 32, BATCH), T, 0, stream>>>(x2, x2_h, x2t);

    // ---- conv: 4 K-chunks (TM=128) -> fp32 partials in convp ----
    mfma_gemm<128, 128, 1, 0, 0, 0, 0, 1, 0, 0, 1, 1, 1, 0, 0><<<dim3(MT / 128, 1, 4), T, 0, stream>>>(
        x2_h, nullptr, Wt, nullptr, nullptr,
        convp, nullptr, apz, nullptr, nullptr,
        (int)MT, FC_PAD, KCHUNK, D_MODEL, KCOMB, FC_PAD,
        0, 0, 0, MT * FC_PAD);

    // ---- fc: xcnn = tanh(relu(sum partials + bcat) @ fc_w^T + fc_b); AMODE=3, MAP2 ----
    mfma_gemm<128, 128, 3, 2, 1, 0, 1, 0, 0, 2, 1, 128, 6, 0, 0><<<dim3(768, 1, 1), T, 0, stream>>>(
        (const ushort_t*)convp, (const ushort_t*)bcat, fc_wt, fc_b, nullptr,
        nullptr, xcnn, apz, nullptr, nullptr,
        (int)MT, D_MODEL, FC_PAD2, FC_PAD, FC_PAD2, D_MODEL, 0, 0, 0, 0);

    // ---- y1 = x1 @ U + bias_v (rowbias folded exactly); fp16 out; MAP2 ----
    mfma_gemm<128, 128, 0, 0, 1, 0, 1, 0, 0, 2, 1, 128, 6, 0, 0><<<dim3(768, 1, 1), T, 0, stream>>>(
        x1_h, nullptr, Ut, bias_v, nullptr,
        nullptr, y1, apz, nullptr, nullptr,
        (int)MT, D_MODEL, D_MODEL, D_MODEL, D_MODEL, D_MODEL, 0, 0, 0, 0);

    // ---- scores + tile-softmax, all 8 batches; batch = XCD (lin%8); r9-proven ----
    mfma_gemm<128, 128, 0, 0, 0, 0, 1, 0, 0, 1, 8, 16, 16, 1, 0><<<dim3(2048, 1, 1), T, 0, stream>>>(
        y1, nullptr, x2_h, nullptr, nullptr,
        nullptr, nullptr, ap, smS, slS,
        SEQ, SEQ, D_MODEL, D_MODEL, D_MODEL, SEQ,
        NEb, NEb, 0, 0);

    // ---- PV with softmax fix-up: MAP3 (d-tile fastest -> P' panel L2-hot) ----
    mfma_gemm<128, 128, 0, 2, 0, 1, 1, 0, 1, 3, 8, 16, 6, 0, 1><<<dim3(768, 1, 1), T, 0, stream>>>(
        nullptr, nullptr, x2t, nullptr,
        xcnn,
        nullptr, xcnn, ap, smS, slS,
        SEQ, D_MODEL, SEQ, SEQ, SEQ, D_MODEL,
        0, NEb, 0, NEb);

    // ---- final: out = concat(x1, x) @ fcx_w^T + fcx_b; MAP2 ----
    mfma_gemm<128, 128, 2, 0, 1, 0, 0, 0, 0, 2, 1, 128, 6, 0, 0><<<dim3(768, 1, 1), T, 0, stream>>>(
        x1_h, xcnn, fcx_wt, fcx_b, nullptr,
        out, nullptr, apz, nullptr, nullptr,
        (int)MT, D_MODEL, 2 * D_MODEL, D_MODEL, 2 * D_MODEL, D_MODEL, 0, 0, 0, 0);
}

// Round 14
// 329.607 us; speedup vs baseline: 1.0181x; 1.0181x over previous
//
#include <hip/hip_runtime.h>
#include <cmath>

#define D_MODEL 768
#define SEQ 2048
#define BATCH 8
#define FC_PAD 96
#define FC_PAD2 128
#define KCOMB (7 * D_MODEL)   // 5376
#define KCHUNK 2688           // KCOMB/2

typedef unsigned short ushort_t;
typedef _Float16 half_t;
typedef __attribute__((ext_vector_type(8))) _Float16 f16x8;
typedef __attribute__((ext_vector_type(8))) unsigned short u16x8;
typedef __attribute__((ext_vector_type(4))) unsigned short u16x4;
typedef __attribute__((ext_vector_type(4))) float f32x4;

struct Ptr8 { const ushort_t* p[8]; };

__device__ __forceinline__ ushort_t f2h(float x) {
    half_t h = (half_t)x;
    return __builtin_bit_cast(ushort_t, h);
}
__device__ __forceinline__ float h2f(ushort_t u) {
    return (float)__builtin_bit_cast(half_t, u);
}
__device__ __forceinline__ float fast_tanh(float x) {
    float a = fabsf(x);
    float t = __expf(-2.f * a);
    float r = (1.f - t) / (1.f + t);
    return copysignf(r, x);
}
__device__ __forceinline__ void gload16(const ushort_t* g, ushort_t* lbase) {
    __builtin_amdgcn_global_load_lds((const __attribute__((address_space(1))) void*)g,
                                     (__attribute__((address_space(3))) void*)lbase,
                                     16, 0, 0);
}

// ---------------- prep kernels ----------------
__global__ void convert_f16_kernel(const float* __restrict__ src, ushort_t* __restrict__ dst, size_t n4) {
    size_t i = (size_t)blockIdx.x * 256 + threadIdx.x;
    if (i >= n4) return;
    f32x4 x = *(const f32x4*)(src + i * 4);
    u16x4 h;
    #pragma unroll
    for (int j = 0; j < 4; ++j) h[j] = f2h(x[j]);
    *(u16x4*)(dst + i * 4) = h;
}

// x2 fp32 -> x2_h [8][2048][768] fp16 AND x2t [8][768][2048] fp16, one pass
__global__ void convert_x2_kernel(const float* __restrict__ in,
                                  ushort_t* __restrict__ x2h, ushort_t* __restrict__ x2t) {
    __shared__ ushort_t tile[32][33];
    int b = blockIdx.z;
    int s0 = blockIdx.x * 32, d0 = blockIdx.y * 32;
    int tx = threadIdx.x & 31, ty = threadIdx.x >> 5;   // 32 x 8
    const float* inb = in + (size_t)b * SEQ * D_MODEL;
    ushort_t* hb = x2h + (size_t)b * SEQ * D_MODEL;
    ushort_t* tb = x2t + (size_t)b * D_MODEL * SEQ;
    #pragma unroll
    for (int i = 0; i < 4; ++i) {
        int s = s0 + ty + i * 8;
        ushort_t h = f2h(inb[(size_t)s * D_MODEL + d0 + tx]);
        hb[(size_t)s * D_MODEL + d0 + tx] = h;
        tile[ty + i * 8][tx] = h;
    }
    __syncthreads();
    #pragma unroll
    for (int i = 0; i < 4; ++i)
        tb[(size_t)(d0 + ty + i * 8) * SEQ + s0 + tx] = tile[tx][ty + i * 8];
}

// all weight prep in one dispatch: Wcomb fp16 [128][5376] (rows 90..127 zero),
// fc_wt [768][128] zero-padded, fcx_wt [768][1536], Ut [n][k]=U[k][n], bcat[128]
#define R0 (FC_PAD2 * KCOMB)                 // 688128
#define R1 (D_MODEL * FC_PAD2)               // 98304
#define R2 (D_MODEL * 2 * D_MODEL)           // 1179648
#define R3 (D_MODEL * D_MODEL)               // 589824
__global__ void prep_weights_kernel(const float* __restrict__ w7, const float* __restrict__ b7,
                                    const float* __restrict__ w5, const float* __restrict__ b5,
                                    const float* __restrict__ w3, const float* __restrict__ b3,
                                    const float* __restrict__ fc_w, const float* __restrict__ fcx_w,
                                    const float* __restrict__ U,
                                    ushort_t* __restrict__ Wt, ushort_t* __restrict__ fc_wt,
                                    ushort_t* __restrict__ fcx_wt, ushort_t* __restrict__ Ut,
                                    float* __restrict__ bcat) {
    int idx = blockIdx.x * 256 + threadIdx.x;
    if (idx < R0) {
        int o = idx / KCOMB, k = idx - o * KCOMB;
        int t = k / D_MODEL, d = k - t * D_MODEL;
        float v = 0.f;
        if (o < 40) {
            v = w7[(size_t)o * (D_MODEL * 7) + d * 7 + t];
        } else if (o < 70) {
            int t5 = t - 1;
            if (t5 >= 0 && t5 < 5) v = w5[(size_t)(o - 40) * (D_MODEL * 5) + d * 5 + t5];
        } else if (o < 90) {
            int t3 = t - 2;
            if (t3 >= 0 && t3 < 3) v = w3[(size_t)(o - 70) * (D_MODEL * 3) + d * 3 + t3];
        }
        Wt[idx] = f2h(v);
        return;
    }
    idx -= R0;
    if (idx < R1) {
        int o = idx / FC_PAD2, j = idx - o * FC_PAD2;
        fc_wt[idx] = (j < 90) ? f2h(fc_w[o * 90 + j]) : 0;
        return;
    }
    idx -= R1;
    if (idx < R2) {
        fcx_wt[idx] = f2h(fcx_w[idx]);
        return;
    }
    idx -= R2;
    if (idx < R3) {
        int n = idx / D_MODEL, k = idx - n * D_MODEL;
        Ut[idx] = f2h(U[(size_t)k * D_MODEL + n]);
        return;
    }
    idx -= R3;
    if (idx < FC_PAD2) {
        float bv = 0.f;
        if (idx < 40) bv = b7[idx];
        else if (idx < 70) bv = b5[idx - 40];
        else if (idx < 90) bv = b3[idx - 70];
        bcat[idx] = bv;
    }
}

// sum 2 conv partials + bias + relu -> feats fp16 [16384][128] (cols 96.. zero)
__global__ void conv_reduce_kernel(const float* __restrict__ P, const float* __restrict__ bcat,
                                   ushort_t* __restrict__ feats) {
    const size_t MT = (size_t)BATCH * SEQ;
    size_t i = (size_t)blockIdx.x * 256 + threadIdx.x;
    if (i >= MT * FC_PAD2) return;
    int col = (int)(i & (FC_PAD2 - 1));
    size_t row = i >> 7;
    float v = 0.f;
    if (col < FC_PAD) {
        size_t idx = row * FC_PAD + col;
        const size_t st = MT * FC_PAD;
        v = P[idx] + P[idx + st] + bcat[col];
        v = fmaxf(v, 0.f);
    }
    feats[i] = f2h(v);
}

// ---------------- fp16 MFMA GEMM, BK=64, 128B LDS rows + XOR slot swizzle ----------------
// C[M,N] = epilogue( A' @ B'^T ); A' [M][K] fp16, B' [N][K] fp16 (N-major).
// 4 waves (2x2), wave tile 64x64. LDS rows: 64 elems (8 x 16B slots),
// slot ^= (row&7) folded into the GLOBAL source address (rule #21).
// AMODE: 0 plain, 1 im2col(x2_h, VGPR-staged), 2 concat(A|A2, stride 768)
// KSPLIT: blockIdx.z = K-chunk; APTR: A base = ap.p[z]
// MAP: 0 3D grid; 1 lin->{z=lin%ZM, bx=t%GX, by=t/GX}; 2 lin->{xcd A-slice, by fast};
//      3 lin->{z=lin%ZM, by=t%GY, bx=t/GY}  (by fastest: A-panel L2-hot)
// SMEPI: tile-softmax epilogue — P'=exp(S-m_tile128) fp16 -> ap.p[z]; stats -> smw/slw.
// ASCALE: PV mode — prologue builds fp16 alpha[16][128] from stats; A-frags scaled.
template<int TM, int TN, int AMODE, int ACT, int HASBIAS, int HASADD,
         int OUTMODE, int KSPLIT, int APTR, int MAP, int ZM, int GX, int GY,
         int SMEPI, int ASCALE>
__global__ __launch_bounds__(256, 4)
void mfma_gemm(const ushort_t* __restrict__ A, const ushort_t* __restrict__ A2,
               const ushort_t* __restrict__ B, const float* __restrict__ bias,
               const ushort_t* __restrict__ addsrc,
               float* __restrict__ Cf, ushort_t* __restrict__ Ch,
               Ptr8 ap, float* __restrict__ smw, float* __restrict__ slw,
               int M, int N, int K, int lda, int ldb, int ldc,
               size_t sA, size_t sB, size_t sBias, size_t sC) {
    constexpr int WM = TM / 2, WN = TN / 2, FM = WM / 16, FN = WN / 16;
    __shared__ __align__(16) ushort_t As_[TM * 64];
    __shared__ __align__(16) ushort_t Bs_[TN * 64];
    __shared__ float pmS[SMEPI ? 4 : 1][SMEPI ? 64 : 1];
    __shared__ float msS[SMEPI ? 128 : 1];
    __shared__ float plS[SMEPI ? 4 : 1][SMEPI ? 64 : 1];
    __shared__ ushort_t alS[ASCALE ? 16 : 1][ASCALE ? 128 : 1];   // fp16 alpha

    int bx, by, z;
    if (MAP == 1) {
        int lin = blockIdx.x;
        z = lin % ZM;
        int t = lin / ZM;
        bx = t % GX;
        by = t / GX;
    } else if (MAP == 2) {
        int lin = blockIdx.x;
        int xcd = lin & 7;
        int t = lin >> 3;
        by = t % GY;
        bx = xcd * (GX / 8) + t / GY;
        z = 0;
    } else if (MAP == 3) {
        int lin = blockIdx.x;
        z = lin % ZM;
        int t = lin / ZM;
        by = t % GY;
        bx = t / GY;
    } else {
        bx = blockIdx.x; by = blockIdx.y; z = blockIdx.z;
    }

    const int kb = KSPLIT ? z * K : 0;
    const ushort_t* Ab = APTR ? ap.p[z] : (A + (KSPLIT ? 0 : (size_t)z * sA));
    const ushort_t* Bb = B + (KSPLIT ? 0 : (size_t)z * sB);
    if (HASBIAS) bias += (size_t)z * sBias;
    if (HASADD) addsrc += (size_t)z * sC;
    if (OUTMODE == 0) Cf += (size_t)z * sC;
    else if (!SMEPI) Ch += (size_t)z * sC;

    const int m0 = bx * TM;
    const int n0 = by * TN;
    const int tid = threadIdx.x;
    const int lane = tid & 63;
    const int wave = tid >> 6;
    const int wm = (wave >> 1) * WM, wn = (wave & 1) * WN;
    const int r16 = lane & 15, kq = lane >> 4;
    const int srow = tid >> 3;          // 0..31
    const int slot = tid & 7;           // 16B slot (LDS-linear)

    // ---- ASCALE prologue: fp16 alpha[tile16][row] from stats ----
    if (ASCALE) {
        if (tid < 128) {
            int row = tid;
            int gm = m0 + row;
            float mt[16], al[16];
            float mg = -3.0e38f;
            #pragma unroll
            for (int t = 0; t < 16; ++t) {
                mt[t] = smw[((size_t)z * 16 + t) * SEQ + gm];
                mg = fmaxf(mg, mt[t]);
            }
            float lg = 0.f;
            #pragma unroll
            for (int t = 0; t < 16; ++t) {
                float e = __expf(mt[t] - mg);
                lg += slw[((size_t)z * 16 + t) * SEQ + gm] * e;
                al[t] = e;
            }
            float inv = 1.f / lg;
            #pragma unroll
            for (int t = 0; t < 16; ++t) alS[t][row] = f2h(al[t] * inv);
        }
        __syncthreads();
    }

    f32x4 acc[FM][FN];
    #pragma unroll
    for (int i = 0; i < FM; ++i)
        #pragma unroll
        for (int j = 0; j < FN; ++j) acc[i][j] = (f32x4){0.f, 0.f, 0.f, 0.f};

    const u16x8 zv = {0, 0, 0, 0, 0, 0, 0, 0};

    for (int k0 = 0; k0 < K; k0 += 64) {
        // ---- stage A ----
        #pragma unroll
        for (int i = 0; i < TM / 32; ++i) {
            int row = i * 32 + srow;
            int gm = m0 + row;
            int xs = slot ^ (row & 7);
            if (AMODE == 1) {
                int gkk = kb + k0 + xs * 8;
                int t = gkk / D_MODEL, d = gkk - t * D_MODEL;
                int s = (gm & (SEQ - 1)) + t - 3;
                int bb = gm >> 11;
                u16x8 v = (s >= 0 && s < SEQ) ? *(const u16x8*)(Ab + ((size_t)(bb * SEQ + s)) * lda + d) : zv;
                *(u16x8*)&As_[(size_t)row * 64 + slot * 8] = v;
            } else {
                const ushort_t* src;
                if (AMODE == 2) {
                    int gk = k0 + xs * 8;
                    src = (gk < D_MODEL) ? Ab + (size_t)gm * D_MODEL + gk
                                         : A2 + (size_t)gm * D_MODEL + (gk - D_MODEL);
                } else {
                    int gk = kb + k0 + xs * 8;
                    src = Ab + (size_t)gm * lda + gk;
                }
                gload16(src, &As_[(size_t)(i * 32 + wave * 8) * 64]);
            }
        }
        // ---- stage B ----
        #pragma unroll
        for (int i = 0; i < TN / 32; ++i) {
            int row = i * 32 + srow;
            int gn = n0 + row;
            int xs = slot ^ (row & 7);
            int gk = kb + k0 + xs * 8;
            gload16(Bb + (size_t)gn * ldb + gk, &Bs_[(size_t)(i * 32 + wave * 8) * 64]);
        }
        __syncthreads();

        f16x8 ah[FM][2], bh[FN][2];
        #pragma unroll
        for (int mi = 0; mi < FM; ++mi) {
            int row = wm + mi * 16 + r16;
            #pragma unroll
            for (int kk = 0; kk < 2; ++kk)
                ah[mi][kk] = *(const f16x8*)&As_[(size_t)row * 64 + (((kk * 4 + kq) ^ (row & 7)) * 8)];
        }
        if (ASCALE) {
            const int kt = k0 >> 7;   // 128-col stats tile
            #pragma unroll
            for (int mi = 0; mi < FM; ++mi) {
                half_t s = __builtin_bit_cast(half_t, alS[kt][wm + mi * 16 + r16]);
                ah[mi][0] = ah[mi][0] * s;
                ah[mi][1] = ah[mi][1] * s;
            }
        }
        #pragma unroll
        for (int ni = 0; ni < FN; ++ni) {
            int row = wn + ni * 16 + r16;
            #pragma unroll
            for (int kk = 0; kk < 2; ++kk)
                bh[ni][kk] = *(const f16x8*)&Bs_[(size_t)row * 64 + (((kk * 4 + kq) ^ (row & 7)) * 8)];
        }
        #pragma unroll
        for (int kk = 0; kk < 2; ++kk)
            #pragma unroll
            for (int mi = 0; mi < FM; ++mi)
                #pragma unroll
                for (int ni = 0; ni < FN; ++ni)
                    acc[mi][ni] = __builtin_amdgcn_mfma_f32_16x16x32_f16(ah[mi][kk], bh[ni][kk], acc[mi][ni], 0, 0, 0);
        __syncthreads();
    }

    if (SMEPI) {
        // ---- tile-softmax epilogue (TM=TN=128, full tiles) ----
        float pmax[FM][4];
        #pragma unroll
        for (int mi = 0; mi < FM; ++mi)
            #pragma unroll
            for (int r = 0; r < 4; ++r) {
                float mx = -3.0e38f;
                #pragma unroll
                for (int ni = 0; ni < FN; ++ni) {
                    float v = acc[mi][ni][r];
                    if (HASBIAS) { v += bias[n0 + wn + ni * 16 + r16]; acc[mi][ni][r] = v; }
                    mx = fmaxf(mx, v);
                }
                mx = fmaxf(mx, __shfl_xor(mx, 1));
                mx = fmaxf(mx, __shfl_xor(mx, 2));
                mx = fmaxf(mx, __shfl_xor(mx, 4));
                mx = fmaxf(mx, __shfl_xor(mx, 8));
                pmax[mi][r] = mx;
            }
        if (r16 == 0) {
            #pragma unroll
            for (int mi = 0; mi < FM; ++mi)
                #pragma unroll
                for (int r = 0; r < 4; ++r)
                    pmS[wave][mi * 16 + kq * 4 + r] = pmax[mi][r];
        }
        __syncthreads();
        if (tid < 128) {                      // combine wn-halves
            int rl = tid & 63, grp = tid >> 6;
            msS[grp * 64 + rl] = fmaxf(pmS[grp * 2][rl], pmS[grp * 2 + 1][rl]);
        }
        __syncthreads();
        #pragma unroll
        for (int mi = 0; mi < FM; ++mi)
            #pragma unroll
            for (int r = 0; r < 4; ++r) {
                float mrow = msS[wm + mi * 16 + kq * 4 + r];
                float s = 0.f;
                #pragma unroll
                for (int ni = 0; ni < FN; ++ni) {
                    float e = __expf(acc[mi][ni][r] - mrow);
                    acc[mi][ni][r] = e;
                    s += e;
                }
                s += __shfl_xor(s, 1);
                s += __shfl_xor(s, 2);
                s += __shfl_xor(s, 4);
                s += __shfl_xor(s, 8);
                pmax[mi][r] = s;
            }
        if (r16 == 0) {
            #pragma unroll
            for (int mi = 0; mi < FM; ++mi)
                #pragma unroll
                for (int r = 0; r < 4; ++r)
                    plS[wave][mi * 16 + kq * 4 + r] = pmax[mi][r];
        }
        __syncthreads();
        if (tid < 128) {                      // write stats
            int rl = tid & 63, grp = tid >> 6;
            int row = grp * 64 + rl;
            float l2 = plS[grp * 2][rl] + plS[grp * 2 + 1][rl];
            size_t si = ((size_t)z * 16 + by) * SEQ + (m0 + row);
            smw[si] = msS[row];
            slw[si] = l2;
        }
        ushort_t* Co = (ushort_t*)ap.p[z];
        #pragma unroll
        for (int mi = 0; mi < FM; ++mi)
            #pragma unroll
            for (int ni = 0; ni < FN; ++ni)
                #pragma unroll
                for (int r = 0; r < 4; ++r) {
                    int gm = m0 + wm + mi * 16 + kq * 4 + r;
                    int gn = n0 + wn + ni * 16 + r16;
                    Co[(size_t)gm * SEQ + gn] = f2h(acc[mi][ni][r]);
                }
        return;
    }

    // ---- standard epilogue ----
    #pragma unroll
    for (int mi = 0; mi < FM; ++mi)
        #pragma unroll
        for (int ni = 0; ni < FN; ++ni)
            #pragma unroll
            for (int r = 0; r < 4; ++r) {
                int gm = m0 + wm + mi * 16 + kq * 4 + r;
                int gn = n0 + wn + ni * 16 + r16;
                if (gn >= N) continue;
                float v = acc[mi][ni][r];
                if (HASBIAS) v += bias[gn];
                if (ACT == 1) v = fmaxf(v, 0.f);
                else if (ACT == 2) v = fast_tanh(v);
                if (HASADD) v += h2f(addsrc[(size_t)gm * ldc + gn]);
                size_t idx = (size_t)gm * ldc + gn;
                if (OUTMODE == 0) Cf[idx] = v;
                else Ch[idx] = f2h(v);
            }
}

extern "C" void kernel_launch(void* const* d_in, const int* in_sizes, int n_in,
                              void* d_out, int out_size, void* d_ws, size_t ws_size,
                              hipStream_t stream) {
    const float* x1     = (const float*)d_in[0];
    const float* x2     = (const float*)d_in[1];
    const float* w7     = (const float*)d_in[2];
    const float* b7     = (const float*)d_in[3];
    const float* w5     = (const float*)d_in[4];
    const float* b5     = (const float*)d_in[5];
    const float* w3     = (const float*)d_in[6];
    const float* b3     = (const float*)d_in[7];
    const float* U      = (const float*)d_in[8];
    const float* bias_v = (const float*)d_in[9];
    const float* fc_w   = (const float*)d_in[10];
    const float* fc_b   = (const float*)d_in[11];
    const float* fcx_w  = (const float*)d_in[12];
    const float* fcx_b  = (const float*)d_in[13];
    float* out = (float*)d_out;

    const size_t MT = (size_t)BATCH * SEQ;      // 16384
    const size_t NE = MT * D_MODEL;             // 12.58M
    const size_t NEb = (size_t)SEQ * D_MODEL;   // per-batch elems
    const size_t SEGSZ = (size_t)SEQ * SEQ;     // P' batch elems (8.39MB fp16)

    char* p = (char*)d_ws;
    auto alloc = [&](size_t bytes) -> char* {
        char* r = p;
        p += (bytes + 255) & ~(size_t)255;
        return r;
    };
    ushort_t* x1_h   = (ushort_t*)alloc(NE * 2);
    ushort_t* x2_h   = (ushort_t*)alloc(NE * 2);
    ushort_t* x2t    = (ushort_t*)alloc(NE * 2);
    ushort_t* y1     = (ushort_t*)alloc(NE * 2);
    ushort_t* xcnn   = (ushort_t*)alloc(NE * 2);
    float*    convp  = (float*)   alloc(MT * FC_PAD * 4 * 4); // 2 partials; then 3 P' segs
    ushort_t* feats  = (ushort_t*)alloc(MT * FC_PAD2 * 2);
    ushort_t* Wt     = (ushort_t*)alloc((size_t)FC_PAD2 * KCOMB * 2);
    ushort_t* fc_wt  = (ushort_t*)alloc((size_t)D_MODEL * FC_PAD2 * 2);
    ushort_t* fcx_wt = (ushort_t*)alloc((size_t)D_MODEL * 2 * D_MODEL * 2);
    ushort_t* Ut     = (ushort_t*)alloc((size_t)D_MODEL * D_MODEL * 2);
    float*    bcat   = (float*)alloc(FC_PAD2 * 4);
    float*    smS    = (float*)alloc((size_t)BATCH * 16 * SEQ * 4);  // tile row-max
    float*    slS    = (float*)alloc((size_t)BATCH * 16 * SEQ * 4);  // tile row-sum

    // P' segments (8 x 8.39MB): 3 in convp (dead after conv_reduce), 5 in d_out
    ushort_t* dob = (ushort_t*)d_out;
    Ptr8 ap;
    ap.p[0] = (ushort_t*)convp;
    ap.p[1] = (ushort_t*)convp + SEGSZ;
    ap.p[2] = (ushort_t*)convp + 2 * SEGSZ;
    ap.p[3] = dob;
    ap.p[4] = dob + SEGSZ;
    ap.p[5] = dob + 2 * SEGSZ;
    ap.p[6] = dob + 3 * SEGSZ;
    ap.p[7] = dob + 4 * SEGSZ;
    Ptr8 apz = {};

    const int T = 256;
    auto blk = [](size_t n) { return dim3((unsigned)((n + 255) / 256)); };

    // ---- prep (3 dispatches) ----
    prep_weights_kernel<<<blk((size_t)R0 + R1 + R2 + R3 + FC_PAD2), T, 0, stream>>>(
        w7, b7, w5, b5, w3, b3, fc_w, fcx_w, U, Wt, fc_wt, fcx_wt, Ut, bcat);
    convert_f16_kernel<<<blk(NE / 4), T, 0, stream>>>(x1, x1_h, NE / 4);
    convert_x2_kernel<<<dim3(SEQ / 32, D_MODEL / 32, BATCH), T, 0, stream>>>(x2, x2_h, x2t);

    // ---- conv: 2 K-chunks -> fp32 partials, then reduce+bias+relu -> feats ----
    mfma_gemm<64, 128, 1, 0, 0, 0, 0, 1, 0, 0, 1, 1, 1, 0, 0><<<dim3(MT / 64, 1, 2), T, 0, stream>>>(
        x2_h, nullptr, Wt, nullptr, nullptr,
        convp, nullptr, apz, nullptr, nullptr,
        (int)MT, FC_PAD, KCHUNK, D_MODEL, KCOMB, FC_PAD,
        0, 0, 0, MT * FC_PAD);
    conv_reduce_kernel<<<blk(MT * FC_PAD2), T, 0, stream>>>(convp, bcat, feats);

    // ---- fc: xcnn = tanh(feats @ fc_w^T + fc_b); MAP2 panel-sliced ----
    mfma_gemm<128, 128, 0, 2, 1, 0, 1, 0, 0, 2, 1, 128, 6, 0, 0><<<dim3(768, 1, 1), T, 0, stream>>>(
        feats, nullptr, fc_wt, fc_b, nullptr,
        nullptr, xcnn, apz, nullptr, nullptr,
        (int)MT, D_MODEL, FC_PAD2, FC_PAD2, FC_PAD2, D_MODEL, 0, 0, 0, 0);

    // ---- y1 = x1 @ U + bias_v (rowbias folded exactly); fp16 out; MAP2 ----
    mfma_gemm<128, 128, 0, 0, 1, 0, 1, 0, 0, 2, 1, 128, 6, 0, 0><<<dim3(768, 1, 1), T, 0, stream>>>(
        x1_h, nullptr, Ut, bias_v, nullptr,
        nullptr, y1, apz, nullptr, nullptr,
        (int)MT, D_MODEL, D_MODEL, D_MODEL, D_MODEL, D_MODEL, 0, 0, 0, 0);

    // ---- scores + tile-softmax, all 8 batches; batch = XCD (lin%8); r9-proven ----
    mfma_gemm<128, 128, 0, 0, 0, 0, 1, 0, 0, 1, 8, 16, 16, 1, 0><<<dim3(2048, 1, 1), T, 0, stream>>>(
        y1, nullptr, x2_h, nullptr, nullptr,
        nullptr, nullptr, ap, smS, slS,
        SEQ, SEQ, D_MODEL, D_MODEL, D_MODEL, SEQ,
        NEb, NEb, 0, 0);

    // ---- PV with softmax fix-up: MAP3 (d-tile fastest -> P' panel L2-hot) ----
    mfma_gemm<128, 128, 0, 2, 0, 1, 1, 0, 1, 3, 8, 16, 6, 0, 1><<<dim3(768, 1, 1), T, 0, stream>>>(
        nullptr, nullptr, x2t, nullptr,
        xcnn,
        nullptr, xcnn, ap, smS, slS,
        SEQ, D_MODEL, SEQ, SEQ, SEQ, D_MODEL,
        0, NEb, 0, NEb);

    // ---- final: out = concat(x1, x) @ fcx_w^T + fcx_b; MAP2 ----
    mfma_gemm<128, 128, 2, 0, 1, 0, 0, 0, 0, 2, 1, 128, 6, 0, 0><<<dim3(768, 1, 1), T, 0, stream>>>(
        x1_h, xcnn, fcx_wt, fcx_b, nullptr,
        out, nullptr, apz, nullptr, nullptr,
        (int)MT, D_MODEL, 2 * D_MODEL, D_MODEL, 2 * D_MODEL, D_MODEL, 0, 0, 0, 0);
}